// Round 15
// baseline (4885.106 us; speedup 1.0000x reference)
//
#include <hip/hip_runtime.h>
#include <float.h>

#define NB   8
#define NC   512
#define NT   4096
#define NCB  32
#define NK   1024
#define ND   32

// Eigen TensorContraction k-panel boundaries for K=512 (XLA:CPU jaxref,
// kc=136). VERIFIED bit-exact in R10.
#define KP0  0
#define KP1  136
#define KP2  272
#define KP3  408
#define KP4  512

// ---- XLA:CPU (Eigen) bit-exact models (verified R10) -------------------------
__device__ __forceinline__ float dot_xla(const float* __restrict__ rf,
                                         const float* __restrict__ c) {
    float t = 0.f;
#pragma unroll
    for (int i = 0; i < ND; ++i) t = fmaf(rf[i], c[i], t);
    return t;
}

__device__ __forceinline__ float cn_xla(const float* __restrict__ c) {
    float t = 0.f;
#pragma unroll
    for (int i = 0; i < ND; ++i) t = fmaf(c[i], c[i], t);
    return t;
}

__device__ __forceinline__ float exact_d_ref(const float* __restrict__ rf,
                                             const float* __restrict__ c) {
    return __fsub_rn(cn_xla(c), __fmul_rn(2.0f, dot_xla(rf, c)));
}

// 512 threads = 8 waves; grid fixed at 512 blocks -> 2 blocks/CU, 16 waves/CU.
// The backend pins this kernel at the 64-VGPR bucket regardless of
// launch_bounds/waves_per_eu/LDS shaping (R12-R14). So the kernel is
// restructured to FIT 64 VGPRs: rf[32] is live across the stage body, so all
// load clustering is capped at <=4 float4 in flight (unroll 1/2).
__global__ void
__attribute__((amdgpu_flat_work_group_size(512, 512)))
__attribute__((amdgpu_waves_per_eu(2, 4)))
rvq_kernel(const float* __restrict__ latent,
           const float* __restrict__ projw,
           const float* __restrict__ projb,
           const float* __restrict__ cb,
           float* __restrict__ out)
{
    // sbuf: phase-B panel staging (17408 B) / phase-C cnf[1024]+mrg (12288 B).
    // xbuf: 9216 B. Total 26.6 KB.
    __shared__ float sbuf[32 * 136];
    __shared__ float xbuf[64 * 36];

    const int tid  = threadIdx.x;
    const int lane = tid & 63;
    const int wv   = tid >> 6;                        // 0..7
    const int b    = blockIdx.x >> 6;                 // 64 blocks per batch
    const int t    = ((blockIdx.x & 63) << 6) + lane; // token column

    // ---------- Phase B: projection — Eigen 4-panel kc=136 model ----------
    {
#pragma clang fp contract(off)
        const float* lat = latent + (size_t)b * NC * NT + t;
        const int d0 = wv * 4;                        // this wave's 4 dims
        float xv[4];
#pragma unroll
        for (int j = 0; j < 4; ++j) xv[j] = 0.f;

#pragma unroll 1
        for (int p = 0; p < 4; ++p) {
            const int c0  = (p == 0) ? KP0 : (p == 1) ? KP1 : (p == 2) ? KP2 : KP3;
            const int len = ((p == 0) ? KP1 : (p == 1) ? KP2 : (p == 2) ? KP3 : KP4) - c0;

            __syncthreads();              // previous panel's sbuf reads done
#pragma unroll
            for (int j = 0; j < 4; ++j)
                for (int cc = lane; cc < len; cc += 64)
                    sbuf[(d0 + j) * len + cc] = projw[(d0 + j) * NC + c0 + cc];
            __syncthreads();

            float acc[4];
#pragma unroll
            for (int j = 0; j < 4; ++j) acc[j] = 0.f;
#pragma unroll 2
            for (int cc = 0; cc < len; ++cc) {
                const float lv = lat[(size_t)(c0 + cc) * NT];
#pragma unroll
                for (int j = 0; j < 4; ++j)
                    acc[j] = fmaf(sbuf[(d0 + j) * len + cc], lv, acc[j]);
            }
            if (p == 0) {
#pragma unroll
                for (int j = 0; j < 4; ++j) xv[j] = acc[j];
            } else {
#pragma unroll
                for (int j = 0; j < 4; ++j) xv[j] = __fadd_rn(xv[j], acc[j]);
            }
        }
#pragma unroll
        for (int j = 0; j < 4; ++j)
            xbuf[lane * 36 + d0 + j] = __fadd_rn(xv[j], projb[d0 + j]);
    }
    __syncthreads();

    // residual in registers (f32, elementwise — matches ref exactly).
    float rf[ND];
#pragma unroll
    for (int d = 0; d < ND; ++d) rf[d] = xbuf[lane * 36 + d];

    float*  cnf = sbuf;                  // aliases w staging (Phase B done)
    float4* mrg = (float4*)(sbuf + 1024);

    // ---------- Phase C: 32 residual-VQ stages ----------
    for (int s = 0; s < NCB; ++s) {
        const float* cbs = cb + (size_t)s * NK * ND;

        __syncthreads();                 // prior-stage mrg / phase-B sbuf reads done

        // fast cnorm (filter only): 1024 candidates over 512 threads.
        // unroll capped so <=4 float4 loads are in flight (rf[] is live!).
#pragma unroll 1
        for (int u = 0; u < 2; ++u) {
            const int k = u * 512 + tid;
            const float4* c4 = (const float4*)(cbs + ((size_t)k << 5));
            float ss = 0.f;
#pragma unroll 2
            for (int j = 0; j < 4; ++j) {
                const float4 va = c4[2 * j];
                const float4 vb = c4[2 * j + 1];
                ss = fmaf(va.x, va.x, ss); ss = fmaf(va.y, va.y, ss);
                ss = fmaf(va.z, va.z, ss); ss = fmaf(va.w, va.w, ss);
                ss = fmaf(vb.x, vb.x, ss); ss = fmaf(vb.y, vb.y, ss);
                ss = fmaf(vb.z, vb.z, ss); ss = fmaf(vb.w, vb.w, ss);
            }
            cnf[k] = ss;
        }
        __syncthreads();

        // ---- fast FMA filter scan over this wave's 128 candidates ----
        float m1 = FLT_MAX, m2 = FLT_MAX;
        int   i1 = 0x7fffffff, i2 = 0x7fffffff;
        const int kbase = __builtin_amdgcn_readfirstlane(wv * 128);

#pragma unroll 1
        for (int kk = 0; kk < 128; ++kk) {
            const int k = kbase + kk;
            const float4* c4 = (const float4*)(cbs + ((size_t)k << 5));
            float a0 = 0.f, a1 = 0.f, a2 = 0.f, a3 = 0.f;
#pragma unroll 2
            for (int j = 0; j < 4; ++j) {
                const float4 va = c4[2 * j];
                const float4 vb = c4[2 * j + 1];
                const int o = j * 8;
                a0 = fmaf(va.x, rf[o + 0], a0);  a1 = fmaf(va.y, rf[o + 1], a1);
                a2 = fmaf(va.z, rf[o + 2], a2);  a3 = fmaf(va.w, rf[o + 3], a3);
                a0 = fmaf(vb.x, rf[o + 4], a0);  a1 = fmaf(vb.y, rf[o + 5], a1);
                a2 = fmaf(vb.z, rf[o + 6], a2);  a3 = fmaf(vb.w, rf[o + 7], a3);
            }
            const float dot  = (a0 + a1) + (a2 + a3);
            const float dist = fmaf(-2.f, dot, cnf[k]);

            const bool l1 = dist < m1;
            const bool l2 = dist < m2;
            m2 = l1 ? m1 : (l2 ? dist : m2);
            i2 = l1 ? i1 : (l2 ? k : i2);
            m1 = l1 ? dist : m1;
            i1 = l1 ? k : i1;
        }

        mrg[wv * 64 + lane] = make_float4(m1, __int_as_float(i1), m2, __int_as_float(i2));
        __syncthreads();

        // ---- cross-wave top-2 merge (all waves redundantly, identical result) ----
        float M1 = FLT_MAX, M2 = FLT_MAX;
        int   I1 = 0x7fffffff, I2 = 0x7fffffff;
#pragma unroll 2
        for (int w2 = 0; w2 < 8; ++w2) {
            const float4 v = mrg[w2 * 64 + lane];
#pragma unroll
            for (int h = 0; h < 2; ++h) {
                const float m = (h == 0) ? v.x : v.z;
                const int   i = __float_as_int((h == 0) ? v.y : v.w);
                const bool b1 = (m < M1) || (m == M1 && i < I1);
                const bool b2 = (m < M2) || (m == M2 && i < I2);
                if (b1) { M2 = M1; I2 = I1; M1 = m; I1 = i; }
                else if (b2) { M2 = m; I2 = i; }
            }
        }

        // ---- exact-ref refine: decide between the two filter candidates ----
        const float d1 = exact_d_ref(rf, cbs + ((size_t)I1 << 5));
        const float d2 = exact_d_ref(rf, cbs + ((size_t)I2 << 5));
        const int kf = (d2 < d1 || (d2 == d1 && I2 < I1)) ? I2 : I1;

        // ---- update residual (elementwise f32, matches ref) ----
        {
#pragma clang fp contract(off)
            const float4* pf = (const float4*)(cbs + ((size_t)kf << 5));
#pragma unroll 2
            for (int j = 0; j < 8; ++j) {
                const float4 v = pf[j];
                const int o = j * 4;
                rf[o + 0] = __fsub_rn(rf[o + 0], v.x);
                rf[o + 1] = __fsub_rn(rf[o + 1], v.y);
                rf[o + 2] = __fsub_rn(rf[o + 2], v.z);
                rf[o + 3] = __fsub_rn(rf[o + 3], v.w);
            }
        }

        if (wv == 0)
            out[(size_t)NB * ND * NT + ((size_t)s * NB + b) * NT + t] = (float)kf;
    }

    // ---------- quantized output [B][D][T]: x - rf_final ≈ x + (qsum - x) ----------
    if (wv == 0) {
#pragma clang fp contract(off)
#pragma unroll
        for (int d = 0; d < ND; ++d) {
            const float x = xbuf[lane * 36 + d];
            out[((size_t)b * ND + d) * NT + t] = __fsub_rn(x, rf[d]);
        }
    }
}

extern "C" void kernel_launch(void* const* d_in, const int* in_sizes, int n_in,
                              void* d_out, int out_size, void* d_ws, size_t ws_size,
                              hipStream_t stream) {
    const float* latent = (const float*)d_in[0];
    const float* projw  = (const float*)d_in[1];
    const float* projb  = (const float*)d_in[2];
    const float* cb     = (const float*)d_in[3];
    float* out = (float*)d_out;

    dim3 grid(NB * NT / 64);   // 512 blocks, 64 tokens each
    dim3 block(512);           // 8 waves
    hipLaunchKernelGGL(rvq_kernel, grid, block, 0, stream,
                       latent, projw, projb, cb, out);
}

// Round 16
// 4211.449 us; speedup vs baseline: 1.1600x; 1.1600x over previous
//
#include <hip/hip_runtime.h>
#include <float.h>

#define NB   8
#define NC   512
#define NT   4096
#define NCB  32
#define NK   1024
#define ND   32

// Eigen TensorContraction k-panel boundaries for K=512 (XLA:CPU jaxref,
// kc=136). VERIFIED bit-exact in R10.
#define KP0  0
#define KP1  136
#define KP2  272
#define KP3  408
#define KP4  512

// ---- XLA:CPU (Eigen) bit-exact models (verified R10) -------------------------
__device__ __forceinline__ float dot_xla(const float* __restrict__ rf,
                                         const float* __restrict__ c) {
    float t = 0.f;
#pragma unroll
    for (int i = 0; i < ND; ++i) t = fmaf(rf[i], c[i], t);
    return t;
}

__device__ __forceinline__ float cn_xla(const float* __restrict__ c) {
    float t = 0.f;
#pragma unroll
    for (int i = 0; i < ND; ++i) t = fmaf(c[i], c[i], t);
    return t;
}

__device__ __forceinline__ float exact_d_ref(const float* __restrict__ rf,
                                             const float* __restrict__ c) {
    return __fsub_rn(cn_xla(c), __fmul_rn(2.0f, dot_xla(rf, c)));
}

// 512 threads = 8 waves; 512 blocks -> 2 blocks/CU, 4 waves/SIMD.
// The backend pins this kernel at the 64-VGPR bucket (R12-R14), so deep
// pipelining of GLOBAL loads in the scan spills rf[32]. Instead the codebook
// is staged into LDS in 32-KB quarters: scan reads are wave-uniform LDS
// broadcasts (conflict-free, short latency, shallow buffering -> no spills).
__global__ void
__attribute__((amdgpu_flat_work_group_size(512, 512)))
__attribute__((amdgpu_waves_per_eu(2, 4)))
rvq_kernel(const float* __restrict__ latent,
           const float* __restrict__ projw,
           const float* __restrict__ projb,
           const float* __restrict__ cb,
           float* __restrict__ out)
{
    __shared__ float  cbuf[8192];        // 32 KB: codebook quarter / phase-B w panel
    __shared__ float  cnf[NK];           // 4 KB: filter cnorms
    __shared__ float4 mrg[512];          // 8 KB: per-wave top-2 merge
    __shared__ float  xbuf[64 * 36];     // 9 KB: projected x rows (stride 36)

    const int tid  = threadIdx.x;
    const int lane = tid & 63;
    const int wv   = tid >> 6;                        // 0..7
    const int b    = blockIdx.x >> 6;                 // 64 blocks per batch
    const int t    = ((blockIdx.x & 63) << 6) + lane; // token column

    // ---------- Phase B: projection — Eigen 4-panel kc=136 model ----------
    {
#pragma clang fp contract(off)
        const float* lat = latent + (size_t)b * NC * NT + t;
        const int d0 = wv * 4;                        // this wave's 4 dims
        float xv[4];
#pragma unroll
        for (int j = 0; j < 4; ++j) xv[j] = 0.f;

#pragma unroll 1
        for (int p = 0; p < 4; ++p) {
            const int c0  = (p == 0) ? KP0 : (p == 1) ? KP1 : (p == 2) ? KP2 : KP3;
            const int len = ((p == 0) ? KP1 : (p == 1) ? KP2 : (p == 2) ? KP3 : KP4) - c0;

            __syncthreads();              // previous panel's cbuf reads done
#pragma unroll
            for (int j = 0; j < 4; ++j)
                for (int cc = lane; cc < len; cc += 64)
                    cbuf[(d0 + j) * len + cc] = projw[(d0 + j) * NC + c0 + cc];
            __syncthreads();

            float acc[4];
#pragma unroll
            for (int j = 0; j < 4; ++j) acc[j] = 0.f;
#pragma unroll 2
            for (int cc = 0; cc < len; ++cc) {
                const float lv = lat[(size_t)(c0 + cc) * NT];
#pragma unroll
                for (int j = 0; j < 4; ++j)
                    acc[j] = fmaf(cbuf[(d0 + j) * len + cc], lv, acc[j]);
            }
            if (p == 0) {
#pragma unroll
                for (int j = 0; j < 4; ++j) xv[j] = acc[j];
            } else {
#pragma unroll
                for (int j = 0; j < 4; ++j) xv[j] = __fadd_rn(xv[j], acc[j]);
            }
        }
#pragma unroll
        for (int j = 0; j < 4; ++j)
            xbuf[lane * 36 + d0 + j] = __fadd_rn(xv[j], projb[d0 + j]);
    }
    __syncthreads();

    // residual in registers (f32, elementwise — matches ref exactly).
    float rf[ND];
#pragma unroll
    for (int d = 0; d < ND; ++d) rf[d] = xbuf[lane * 36 + d];

    // ---------- Phase C: 32 residual-VQ stages ----------
    for (int s = 0; s < NCB; ++s) {
        const float* cbs = cb + (size_t)s * NK * ND;

        __syncthreads();                 // prior stage's mrg/cbuf reads done

        // fast cnorm (filter only): from global, 1024 candidates / 512 threads
#pragma unroll 1
        for (int u = 0; u < 2; ++u) {
            const int k = u * 512 + tid;
            const float4* c4 = (const float4*)(cbs + ((size_t)k << 5));
            float ss = 0.f;
#pragma unroll 2
            for (int j = 0; j < 4; ++j) {
                const float4 va = c4[2 * j];
                const float4 vb = c4[2 * j + 1];
                ss = fmaf(va.x, va.x, ss); ss = fmaf(va.y, va.y, ss);
                ss = fmaf(va.z, va.z, ss); ss = fmaf(va.w, va.w, ss);
                ss = fmaf(vb.x, vb.x, ss); ss = fmaf(vb.y, vb.y, ss);
                ss = fmaf(vb.z, vb.z, ss); ss = fmaf(vb.w, vb.w, ss);
            }
            cnf[k] = ss;
        }

        // ---- scan in 4 staged quarters of 256 candidates ----
        float m1 = FLT_MAX, m2 = FLT_MAX;
        int   i1 = 0x7fffffff, i2 = 0x7fffffff;

#pragma unroll 1
        for (int q = 0; q < 4; ++q) {
            __syncthreads();             // prev quarter's cbuf reads done (q=0: cnf visible after next sync)
            // stage quarter q: 8192 floats = 2048 float4 over 512 threads
            {
                const float4* gsrc = (const float4*)(cbs + (size_t)q * 256 * ND);
                float4* dst = (float4*)cbuf;
#pragma unroll
                for (int i = 0; i < 4; ++i)
                    dst[i * 512 + tid] = gsrc[i * 512 + tid];
            }
            __syncthreads();

            // wave wv scans local candidates [wv*32, wv*32+32)
            const int klocal0 = __builtin_amdgcn_readfirstlane(wv * 32);
            const int kglob0  = q * 256 + klocal0;

#pragma unroll 2
            for (int c = 0; c < 32; ++c) {
                const float4* c4 = (const float4*)(cbuf + ((klocal0 + c) << 5));
                const int k = kglob0 + c;
                float a0 = 0.f, a1 = 0.f, a2 = 0.f, a3 = 0.f;
#pragma unroll 2
                for (int j = 0; j < 4; ++j) {
                    const float4 va = c4[2 * j];
                    const float4 vb = c4[2 * j + 1];
                    const int o = j * 8;
                    a0 = fmaf(va.x, rf[o + 0], a0);  a1 = fmaf(va.y, rf[o + 1], a1);
                    a2 = fmaf(va.z, rf[o + 2], a2);  a3 = fmaf(va.w, rf[o + 3], a3);
                    a0 = fmaf(vb.x, rf[o + 4], a0);  a1 = fmaf(vb.y, rf[o + 5], a1);
                    a2 = fmaf(vb.z, rf[o + 6], a2);  a3 = fmaf(vb.w, rf[o + 7], a3);
                }
                const float dot  = (a0 + a1) + (a2 + a3);
                const float dist = fmaf(-2.f, dot, cnf[k]);

                const bool l1 = dist < m1;
                const bool l2 = dist < m2;
                m2 = l1 ? m1 : (l2 ? dist : m2);
                i2 = l1 ? i1 : (l2 ? k : i2);
                m1 = l1 ? dist : m1;
                i1 = l1 ? k : i1;
            }
        }

        mrg[wv * 64 + lane] = make_float4(m1, __int_as_float(i1), m2, __int_as_float(i2));
        __syncthreads();

        // ---- cross-wave top-2 merge (all waves redundantly, identical result) ----
        float M1 = FLT_MAX, M2 = FLT_MAX;
        int   I1 = 0x7fffffff, I2 = 0x7fffffff;
#pragma unroll 2
        for (int w2 = 0; w2 < 8; ++w2) {
            const float4 v = mrg[w2 * 64 + lane];
#pragma unroll
            for (int h = 0; h < 2; ++h) {
                const float m = (h == 0) ? v.x : v.z;
                const int   i = __float_as_int((h == 0) ? v.y : v.w);
                const bool b1 = (m < M1) || (m == M1 && i < I1);
                const bool b2 = (m < M2) || (m == M2 && i < I2);
                if (b1) { M2 = M1; I2 = I1; M1 = m; I1 = i; }
                else if (b2) { M2 = m; I2 = i; }
            }
        }

        // ---- exact-ref refine: decide between the two filter candidates ----
        const float d1 = exact_d_ref(rf, cbs + ((size_t)I1 << 5));
        const float d2 = exact_d_ref(rf, cbs + ((size_t)I2 << 5));
        const int kf = (d2 < d1 || (d2 == d1 && I2 < I1)) ? I2 : I1;

        // ---- update residual (elementwise f32, matches ref) ----
        {
#pragma clang fp contract(off)
            const float4* pf = (const float4*)(cbs + ((size_t)kf << 5));
#pragma unroll 2
            for (int j = 0; j < 8; ++j) {
                const float4 v = pf[j];
                const int o = j * 4;
                rf[o + 0] = __fsub_rn(rf[o + 0], v.x);
                rf[o + 1] = __fsub_rn(rf[o + 1], v.y);
                rf[o + 2] = __fsub_rn(rf[o + 2], v.z);
                rf[o + 3] = __fsub_rn(rf[o + 3], v.w);
            }
        }

        if (wv == 0)
            out[(size_t)NB * ND * NT + ((size_t)s * NB + b) * NT + t] = (float)kf;
    }

    // ---------- quantized output [B][D][T]: x - rf_final ≈ x + (qsum - x) ----------
    if (wv == 0) {
#pragma clang fp contract(off)
#pragma unroll
        for (int d = 0; d < ND; ++d) {
            const float x = xbuf[lane * 36 + d];
            out[((size_t)b * ND + d) * NT + t] = __fsub_rn(x, rf[d]);
        }
    }
}

extern "C" void kernel_launch(void* const* d_in, const int* in_sizes, int n_in,
                              void* d_out, int out_size, void* d_ws, size_t ws_size,
                              hipStream_t stream) {
    const float* latent = (const float*)d_in[0];
    const float* projw  = (const float*)d_in[1];
    const float* projb  = (const float*)d_in[2];
    const float* cb     = (const float*)d_in[3];
    float* out = (float*)d_out;

    dim3 grid(NB * NT / 64);   // 512 blocks, 64 tokens each
    dim3 block(512);           // 8 waves
    hipLaunchKernelGGL(rvq_kernel, grid, block, 0, stream,
                       latent, projw, projb, cb, out);
}

// Round 17
// 1837.294 us; speedup vs baseline: 2.6589x; 2.2922x over previous
//
#include <hip/hip_runtime.h>
#include <float.h>

#define NB   8
#define NC   512
#define NT   4096
#define NCB  32
#define NK   1024
#define ND   32

// Eigen TensorContraction k-panel boundaries for K=512 (XLA:CPU jaxref,
// kc=136). VERIFIED bit-exact in R10.
#define KP0  0
#define KP1  136
#define KP2  272
#define KP3  408
#define KP4  512

typedef float f32x16 __attribute__((ext_vector_type(16)));

// ---- XLA:CPU (Eigen) bit-exact models (verified R10) -------------------------
__device__ __forceinline__ float dot_xla(const float* __restrict__ rf,
                                         const float* __restrict__ c) {
    float t = 0.f;
#pragma unroll
    for (int i = 0; i < ND; ++i) t = fmaf(rf[i], c[i], t);
    return t;
}

__device__ __forceinline__ float cn_xla(const float* __restrict__ c) {
    float t = 0.f;
#pragma unroll
    for (int i = 0; i < ND; ++i) t = fmaf(c[i], c[i], t);
    return t;
}

__device__ __forceinline__ float exact_d_ref(const float* __restrict__ rf,
                                             const float* __restrict__ c) {
    return __fsub_rn(cn_xla(c), __fmul_rn(2.0f, dot_xla(rf, c)));
}

// 512 threads = 8 waves; 512 blocks -> 2 blocks/CU, 4 waves/SIMD.
// Scan codeword data is wave-uniform -> fetched via the SCALAR path
// (s_load_dwordx16 -> SGPRs, K$/L2 bandwidth) and consumed as the single
// SGPR operand of v_fma. No vector-memory/LDS broadcast waste (R15/R16
// lesson: uniform ds_read_b128 still moves 1KB/instr), and no deep VGPR
// pipelining -> rf[32] stays resident in the 64-VGPR bucket (R12-14 lesson).
__global__ void
__attribute__((amdgpu_flat_work_group_size(512, 512)))
rvq_kernel(const float* __restrict__ latent,
           const float* __restrict__ projw,
           const float* __restrict__ projb,
           const float* __restrict__ cb,
           float* __restrict__ out)
{
    __shared__ float  sbuf[32 * 136];    // 17 KB: phase-B w-panel staging
    __shared__ float  cnf[NK];           //  4 KB: filter cnorms
    __shared__ float4 mrg[512];          //  8 KB: per-wave top-2 merge
    __shared__ float  xbuf[64 * 36];     //  9 KB: projected x rows (stride 36)

    const int tid  = threadIdx.x;
    const int lane = tid & 63;
    const int wv   = tid >> 6;                        // 0..7
    const int b    = blockIdx.x >> 6;                 // 64 blocks per batch
    const int t    = ((blockIdx.x & 63) << 6) + lane; // token column

    // ---------- Phase B: projection — Eigen 4-panel kc=136 model ----------
    {
#pragma clang fp contract(off)
        const float* lat = latent + (size_t)b * NC * NT + t;
        const int d0 = wv * 4;                        // this wave's 4 dims
        float xv[4];
#pragma unroll
        for (int j = 0; j < 4; ++j) xv[j] = 0.f;

#pragma unroll 1
        for (int p = 0; p < 4; ++p) {
            const int c0  = (p == 0) ? KP0 : (p == 1) ? KP1 : (p == 2) ? KP2 : KP3;
            const int len = ((p == 0) ? KP1 : (p == 1) ? KP2 : (p == 2) ? KP3 : KP4) - c0;

            __syncthreads();              // previous panel's sbuf reads done
#pragma unroll
            for (int j = 0; j < 4; ++j)
                for (int cc = lane; cc < len; cc += 64)
                    sbuf[(d0 + j) * len + cc] = projw[(d0 + j) * NC + c0 + cc];
            __syncthreads();

            float acc[4];
#pragma unroll
            for (int j = 0; j < 4; ++j) acc[j] = 0.f;
#pragma unroll 2
            for (int cc = 0; cc < len; ++cc) {
                const float lv = lat[(size_t)(c0 + cc) * NT];
#pragma unroll
                for (int j = 0; j < 4; ++j)
                    acc[j] = fmaf(sbuf[(d0 + j) * len + cc], lv, acc[j]);
            }
            if (p == 0) {
#pragma unroll
                for (int j = 0; j < 4; ++j) xv[j] = acc[j];
            } else {
#pragma unroll
                for (int j = 0; j < 4; ++j) xv[j] = __fadd_rn(xv[j], acc[j]);
            }
        }
#pragma unroll
        for (int j = 0; j < 4; ++j)
            xbuf[lane * 36 + d0 + j] = __fadd_rn(xv[j], projb[d0 + j]);
    }
    __syncthreads();

    // residual in registers (f32, elementwise — matches ref exactly).
    float rf[ND];
#pragma unroll
    for (int d = 0; d < ND; ++d) rf[d] = xbuf[lane * 36 + d];

    // ---------- Phase C: 32 residual-VQ stages ----------
    for (int s = 0; s < NCB; ++s) {
        const float* cbs = cb + (size_t)s * NK * ND;

        __syncthreads();                 // prior stage's cnf/mrg reads done

        // fast cnorm (filter only): global vector loads, 2 candidates/thread
#pragma unroll 1
        for (int u = 0; u < 2; ++u) {
            const int k = u * 512 + tid;
            const float4* c4 = (const float4*)(cbs + ((size_t)k << 5));
            float ss = 0.f;
#pragma unroll 2
            for (int j = 0; j < 4; ++j) {
                const float4 va = c4[2 * j];
                const float4 vb = c4[2 * j + 1];
                ss = fmaf(va.x, va.x, ss); ss = fmaf(va.y, va.y, ss);
                ss = fmaf(va.z, va.z, ss); ss = fmaf(va.w, va.w, ss);
                ss = fmaf(vb.x, vb.x, ss); ss = fmaf(vb.y, vb.y, ss);
                ss = fmaf(vb.z, vb.z, ss); ss = fmaf(vb.w, vb.w, ss);
            }
            cnf[k] = ss;
        }
        __syncthreads();

        // ---- scalar-path filter scan over this wave's 128 candidates ----
        float m1 = FLT_MAX, m2 = FLT_MAX;
        int   i1 = 0x7fffffff, i2 = 0x7fffffff;
        const int kbase = __builtin_amdgcn_readfirstlane(wv * 128);
        const float* cwbase = cbs + ((size_t)kbase << 5);

#pragma unroll 1
        for (int cc = 0; cc < 128; cc += 2) {
            f32x16 wA, wB, wC, wD;       // 2 candidates = 64 floats in SGPRs
            asm volatile(
                "s_load_dwordx16 %0, %4, 0x0\n\t"
                "s_load_dwordx16 %1, %4, 0x40\n\t"
                "s_load_dwordx16 %2, %4, 0x80\n\t"
                "s_load_dwordx16 %3, %4, 0xc0\n\t"
                "s_waitcnt lgkmcnt(0)"
                : "=&s"(wA), "=&s"(wB), "=&s"(wC), "=&s"(wD)
                : "s"(cwbase + ((size_t)cc << 5)));

            // candidate k0 = kbase+cc (elements wA[0..15], wB[0..15])
            {
                const int k = kbase + cc;
                float a0 = 0.f, a1 = 0.f, a2 = 0.f, a3 = 0.f;
#pragma unroll
                for (int j = 0; j < 4; ++j) {
                    a0 = fmaf(wA[4 * j + 0], rf[4 * j + 0], a0);
                    a1 = fmaf(wA[4 * j + 1], rf[4 * j + 1], a1);
                    a2 = fmaf(wA[4 * j + 2], rf[4 * j + 2], a2);
                    a3 = fmaf(wA[4 * j + 3], rf[4 * j + 3], a3);
                }
#pragma unroll
                for (int j = 0; j < 4; ++j) {
                    a0 = fmaf(wB[4 * j + 0], rf[16 + 4 * j + 0], a0);
                    a1 = fmaf(wB[4 * j + 1], rf[16 + 4 * j + 1], a1);
                    a2 = fmaf(wB[4 * j + 2], rf[16 + 4 * j + 2], a2);
                    a3 = fmaf(wB[4 * j + 3], rf[16 + 4 * j + 3], a3);
                }
                const float dot  = (a0 + a1) + (a2 + a3);
                const float dist = fmaf(-2.f, dot, cnf[k]);
                const bool l1 = dist < m1;
                const bool l2 = dist < m2;
                m2 = l1 ? m1 : (l2 ? dist : m2);
                i2 = l1 ? i1 : (l2 ? k : i2);
                m1 = l1 ? dist : m1;
                i1 = l1 ? k : i1;
            }
            // candidate k1 = kbase+cc+1 (elements wC[0..15], wD[0..15])
            {
                const int k = kbase + cc + 1;
                float a0 = 0.f, a1 = 0.f, a2 = 0.f, a3 = 0.f;
#pragma unroll
                for (int j = 0; j < 4; ++j) {
                    a0 = fmaf(wC[4 * j + 0], rf[4 * j + 0], a0);
                    a1 = fmaf(wC[4 * j + 1], rf[4 * j + 1], a1);
                    a2 = fmaf(wC[4 * j + 2], rf[4 * j + 2], a2);
                    a3 = fmaf(wC[4 * j + 3], rf[4 * j + 3], a3);
                }
#pragma unroll
                for (int j = 0; j < 4; ++j) {
                    a0 = fmaf(wD[4 * j + 0], rf[16 + 4 * j + 0], a0);
                    a1 = fmaf(wD[4 * j + 1], rf[16 + 4 * j + 1], a1);
                    a2 = fmaf(wD[4 * j + 2], rf[16 + 4 * j + 2], a2);
                    a3 = fmaf(wD[4 * j + 3], rf[16 + 4 * j + 3], a3);
                }
                const float dot  = (a0 + a1) + (a2 + a3);
                const float dist = fmaf(-2.f, dot, cnf[k]);
                const bool l1 = dist < m1;
                const bool l2 = dist < m2;
                m2 = l1 ? m1 : (l2 ? dist : m2);
                i2 = l1 ? i1 : (l2 ? k : i2);
                m1 = l1 ? dist : m1;
                i1 = l1 ? k : i1;
            }
        }

        mrg[wv * 64 + lane] = make_float4(m1, __int_as_float(i1), m2, __int_as_float(i2));
        __syncthreads();

        // ---- cross-wave top-2 merge (all waves redundantly, identical result) ----
        float M1 = FLT_MAX, M2 = FLT_MAX;
        int   I1 = 0x7fffffff, I2 = 0x7fffffff;
#pragma unroll 2
        for (int w2 = 0; w2 < 8; ++w2) {
            const float4 v = mrg[w2 * 64 + lane];
#pragma unroll
            for (int h = 0; h < 2; ++h) {
                const float m = (h == 0) ? v.x : v.z;
                const int   i = __float_as_int((h == 0) ? v.y : v.w);
                const bool b1 = (m < M1) || (m == M1 && i < I1);
                const bool b2 = (m < M2) || (m == M2 && i < I2);
                if (b1) { M2 = M1; I2 = I1; M1 = m; I1 = i; }
                else if (b2) { M2 = m; I2 = i; }
            }
        }

        // ---- exact-ref refine: decide between the two filter candidates ----
        const float d1 = exact_d_ref(rf, cbs + ((size_t)I1 << 5));
        const float d2 = exact_d_ref(rf, cbs + ((size_t)I2 << 5));
        const int kf = (d2 < d1 || (d2 == d1 && I2 < I1)) ? I2 : I1;

        // ---- update residual (elementwise f32, matches ref) ----
        {
#pragma clang fp contract(off)
            const float4* pf = (const float4*)(cbs + ((size_t)kf << 5));
#pragma unroll 2
            for (int j = 0; j < 8; ++j) {
                const float4 v = pf[j];
                const int o = j * 4;
                rf[o + 0] = __fsub_rn(rf[o + 0], v.x);
                rf[o + 1] = __fsub_rn(rf[o + 1], v.y);
                rf[o + 2] = __fsub_rn(rf[o + 2], v.z);
                rf[o + 3] = __fsub_rn(rf[o + 3], v.w);
            }
        }

        if (wv == 0)
            out[(size_t)NB * ND * NT + ((size_t)s * NB + b) * NT + t] = (float)kf;
    }

    // ---------- quantized output [B][D][T]: x - rf_final ≈ x + (qsum - x) ----------
    if (wv == 0) {
#pragma clang fp contract(off)
#pragma unroll
        for (int d = 0; d < ND; ++d) {
            const float x = xbuf[lane * 36 + d];
            out[((size_t)b * ND + d) * NT + t] = __fsub_rn(x, rf[d]);
        }
    }
}

extern "C" void kernel_launch(void* const* d_in, const int* in_sizes, int n_in,
                              void* d_out, int out_size, void* d_ws, size_t ws_size,
                              hipStream_t stream) {
    const float* latent = (const float*)d_in[0];
    const float* projw  = (const float*)d_in[1];
    const float* projb  = (const float*)d_in[2];
    const float* cb     = (const float*)d_in[3];
    float* out = (float*)d_out;

    dim3 grid(NB * NT / 64);   // 512 blocks, 64 tokens each
    dim3 block(512);           // 8 waves
    hipLaunchKernelGGL(rvq_kernel, grid, block, 0, stream,
                       latent, projw, projb, cb, out);
}

// Round 18
// 1811.840 us; speedup vs baseline: 2.6962x; 1.0140x over previous
//
#include <hip/hip_runtime.h>
#include <float.h>

#define NB   8
#define NC   512
#define NT   4096
#define NCB  32
#define NK   1024
#define ND   32

// Eigen TensorContraction k-panel boundaries for K=512 (XLA:CPU jaxref,
// kc=136). VERIFIED bit-exact in R10.
#define KP0  0
#define KP1  136
#define KP2  272
#define KP3  408
#define KP4  512

typedef float f32x16 __attribute__((ext_vector_type(16)));

// ---- XLA:CPU (Eigen) bit-exact models (verified R10) -------------------------
__device__ __forceinline__ float dot_xla(const float* __restrict__ rf,
                                         const float* __restrict__ c) {
    float t = 0.f;
#pragma unroll
    for (int i = 0; i < ND; ++i) t = fmaf(rf[i], c[i], t);
    return t;
}

__device__ __forceinline__ float cn_xla(const float* __restrict__ c) {
    float t = 0.f;
#pragma unroll
    for (int i = 0; i < ND; ++i) t = fmaf(c[i], c[i], t);
    return t;
}

__device__ __forceinline__ float exact_d_ref(const float* __restrict__ rf,
                                             const float* __restrict__ c) {
    return __fsub_rn(cn_xla(c), __fmul_rn(2.0f, dot_xla(rf, c)));
}

// 512 threads = 8 waves; 512 blocks -> 2 blocks/CU, 4 waves/SIMD.
// Scan codewords are wave-uniform -> scalar path (s_load_dwordx16 -> SGPRs),
// consumed as the single SGPR operand of v_fma (R17). R18: the scalar loads
// are SOFTWARE-PIPELINED (double-buffered, one batch in flight under each
// compute segment; SMEM is out-of-order so only lgkmcnt(0) drains are used,
// scheduled so each drain has had a full compute segment to complete).
__global__ void
__attribute__((amdgpu_flat_work_group_size(512, 512)))
rvq_kernel(const float* __restrict__ latent,
           const float* __restrict__ projw,
           const float* __restrict__ projb,
           const float* __restrict__ cb,
           float* __restrict__ out)
{
    __shared__ float  sbuf[32 * 136];    // 17 KB: phase-B w-panel staging
    __shared__ float  cnf[NK];           //  4 KB: filter cnorms
    __shared__ float4 mrg[512];          //  8 KB: per-wave top-2 merge
    __shared__ float  xbuf[64 * 36];     //  9 KB: projected x rows (stride 36)

    const int tid  = threadIdx.x;
    const int lane = tid & 63;
    const int wv   = tid >> 6;                        // 0..7
    const int b    = blockIdx.x >> 6;                 // 64 blocks per batch
    const int t    = ((blockIdx.x & 63) << 6) + lane; // token column

    // ---------- Phase B: projection — Eigen 4-panel kc=136 model ----------
    {
#pragma clang fp contract(off)
        const float* lat = latent + (size_t)b * NC * NT + t;
        const int d0 = wv * 4;                        // this wave's 4 dims
        float xv[4];
#pragma unroll
        for (int j = 0; j < 4; ++j) xv[j] = 0.f;

#pragma unroll 1
        for (int p = 0; p < 4; ++p) {
            const int c0  = (p == 0) ? KP0 : (p == 1) ? KP1 : (p == 2) ? KP2 : KP3;
            const int len = ((p == 0) ? KP1 : (p == 1) ? KP2 : (p == 2) ? KP3 : KP4) - c0;

            __syncthreads();              // previous panel's sbuf reads done
#pragma unroll
            for (int j = 0; j < 4; ++j)
                for (int cc = lane; cc < len; cc += 64)
                    sbuf[(d0 + j) * len + cc] = projw[(d0 + j) * NC + c0 + cc];
            __syncthreads();

            float acc[4];
#pragma unroll
            for (int j = 0; j < 4; ++j) acc[j] = 0.f;
#pragma unroll 2
            for (int cc = 0; cc < len; ++cc) {
                const float lv = lat[(size_t)(c0 + cc) * NT];
#pragma unroll
                for (int j = 0; j < 4; ++j)
                    acc[j] = fmaf(sbuf[(d0 + j) * len + cc], lv, acc[j]);
            }
            if (p == 0) {
#pragma unroll
                for (int j = 0; j < 4; ++j) xv[j] = acc[j];
            } else {
#pragma unroll
                for (int j = 0; j < 4; ++j) xv[j] = __fadd_rn(xv[j], acc[j]);
            }
        }
#pragma unroll
        for (int j = 0; j < 4; ++j)
            xbuf[lane * 36 + d0 + j] = __fadd_rn(xv[j], projb[d0 + j]);
    }
    __syncthreads();

    // residual in registers (f32, elementwise — matches ref exactly).
    float rf[ND];
#pragma unroll
    for (int d = 0; d < ND; ++d) rf[d] = xbuf[lane * 36 + d];

    // ---------- Phase C: 32 residual-VQ stages ----------
    for (int s = 0; s < NCB; ++s) {
        const float* cbs = cb + (size_t)s * NK * ND;

        __syncthreads();                 // prior stage's cnf/mrg reads done

        // fast cnorm (filter only): global vector loads, 2 candidates/thread
#pragma unroll 1
        for (int u = 0; u < 2; ++u) {
            const int k = u * 512 + tid;
            const float4* c4 = (const float4*)(cbs + ((size_t)k << 5));
            float ss = 0.f;
#pragma unroll 2
            for (int j = 0; j < 4; ++j) {
                const float4 va = c4[2 * j];
                const float4 vb = c4[2 * j + 1];
                ss = fmaf(va.x, va.x, ss); ss = fmaf(va.y, va.y, ss);
                ss = fmaf(va.z, va.z, ss); ss = fmaf(va.w, va.w, ss);
                ss = fmaf(vb.x, vb.x, ss); ss = fmaf(vb.y, vb.y, ss);
                ss = fmaf(vb.z, vb.z, ss); ss = fmaf(vb.w, vb.w, ss);
            }
            cnf[k] = ss;
        }
        __syncthreads();

        // ---- pipelined scalar-path filter scan: this wave's 128 candidates ----
        float m1 = FLT_MAX, m2 = FLT_MAX;
        int   i1 = 0x7fffffff, i2 = 0x7fffffff;
        const int kbase = __builtin_amdgcn_readfirstlane(wv * 128);
        const float* cwbase = cbs + ((size_t)kbase << 5);

        f32x16 A0, A1, B0, B1;

        auto issue = [&](int cc, f32x16& u0, f32x16& u1) {
            const float* p = cwbase + ((size_t)cc << 5);
            asm volatile("s_load_dwordx16 %0, %2, 0x0\n\t"
                         "s_load_dwordx16 %1, %2, 0x40"
                         : "=&s"(u0), "=&s"(u1) : "s"(p));
            __builtin_amdgcn_sched_barrier(0);   // keep compute below the issue
        };
        auto waitfor = [&](f32x16& u0, f32x16& u1) {
            asm volatile("s_waitcnt lgkmcnt(0)" : "+s"(u0), "+s"(u1));
        };
        auto scan_one = [&](int k, const f32x16& w0, const f32x16& w1) {
            float a0 = 0.f, a1 = 0.f, a2 = 0.f, a3 = 0.f;
#pragma unroll
            for (int j = 0; j < 4; ++j) {
                a0 = fmaf(w0[4 * j + 0], rf[4 * j + 0], a0);
                a1 = fmaf(w0[4 * j + 1], rf[4 * j + 1], a1);
                a2 = fmaf(w0[4 * j + 2], rf[4 * j + 2], a2);
                a3 = fmaf(w0[4 * j + 3], rf[4 * j + 3], a3);
            }
#pragma unroll
            for (int j = 0; j < 4; ++j) {
                a0 = fmaf(w1[4 * j + 0], rf[16 + 4 * j + 0], a0);
                a1 = fmaf(w1[4 * j + 1], rf[16 + 4 * j + 1], a1);
                a2 = fmaf(w1[4 * j + 2], rf[16 + 4 * j + 2], a2);
                a3 = fmaf(w1[4 * j + 3], rf[16 + 4 * j + 3], a3);
            }
            const float dot  = (a0 + a1) + (a2 + a3);
            const float dist = fmaf(-2.f, dot, cnf[k]);
            const bool l1 = dist < m1;
            const bool l2 = dist < m2;
            m2 = l1 ? m1 : (l2 ? dist : m2);
            i2 = l1 ? i1 : (l2 ? k : i2);
            m1 = l1 ? dist : m1;
            i1 = l1 ? k : i1;
        };

        issue(0, A0, A1);                     // prologue: batch A(0) in flight
#pragma unroll 1
        for (int cc = 0; cc < 128; cc += 2) {
            waitfor(A0, A1);                  // A ready (only A outstanding)
            issue(cc + 1, B0, B1);            // B in flight under compute A
            scan_one(kbase + cc, A0, A1);
            waitfor(B0, B1);                  // B ready
            issue((cc + 2) & 127, A0, A1);    // next A (tail: dummy cc=0)
            scan_one(kbase + cc + 1, B0, B1);
        }
        waitfor(A0, A1);                      // drain tail dummy (regs stay live)

        mrg[wv * 64 + lane] = make_float4(m1, __int_as_float(i1), m2, __int_as_float(i2));
        __syncthreads();

        // ---- cross-wave top-2 merge (all waves redundantly, identical result) ----
        float M1 = FLT_MAX, M2 = FLT_MAX;
        int   I1 = 0x7fffffff, I2 = 0x7fffffff;
#pragma unroll 2
        for (int w2 = 0; w2 < 8; ++w2) {
            const float4 v = mrg[w2 * 64 + lane];
#pragma unroll
            for (int h = 0; h < 2; ++h) {
                const float m = (h == 0) ? v.x : v.z;
                const int   i = __float_as_int((h == 0) ? v.y : v.w);
                const bool b1 = (m < M1) || (m == M1 && i < I1);
                const bool b2 = (m < M2) || (m == M2 && i < I2);
                if (b1) { M2 = M1; I2 = I1; M1 = m; I1 = i; }
                else if (b2) { M2 = m; I2 = i; }
            }
        }

        // ---- exact-ref refine: decide between the two filter candidates ----
        const float d1 = exact_d_ref(rf, cbs + ((size_t)I1 << 5));
        const float d2 = exact_d_ref(rf, cbs + ((size_t)I2 << 5));
        const int kf = (d2 < d1 || (d2 == d1 && I2 < I1)) ? I2 : I1;

        // ---- update residual (elementwise f32, matches ref) ----
        {
#pragma clang fp contract(off)
            const float4* pf = (const float4*)(cbs + ((size_t)kf << 5));
#pragma unroll 2
            for (int j = 0; j < 8; ++j) {
                const float4 v = pf[j];
                const int o = j * 4;
                rf[o + 0] = __fsub_rn(rf[o + 0], v.x);
                rf[o + 1] = __fsub_rn(rf[o + 1], v.y);
                rf[o + 2] = __fsub_rn(rf[o + 2], v.z);
                rf[o + 3] = __fsub_rn(rf[o + 3], v.w);
            }
        }

        if (wv == 0)
            out[(size_t)NB * ND * NT + ((size_t)s * NB + b) * NT + t] = (float)kf;
    }

    // ---------- quantized output [B][D][T]: x - rf_final ≈ x + (qsum - x) ----------
    if (wv == 0) {
#pragma clang fp contract(off)
#pragma unroll
        for (int d = 0; d < ND; ++d) {
            const float x = xbuf[lane * 36 + d];
            out[((size_t)b * ND + d) * NT + t] = __fsub_rn(x, rf[d]);
        }
    }
}

extern "C" void kernel_launch(void* const* d_in, const int* in_sizes, int n_in,
                              void* d_out, int out_size, void* d_ws, size_t ws_size,
                              hipStream_t stream) {
    const float* latent = (const float*)d_in[0];
    const float* projw  = (const float*)d_in[1];
    const float* projb  = (const float*)d_in[2];
    const float* cb     = (const float*)d_in[3];
    float* out = (float*)d_out;

    dim3 grid(NB * NT / 64);   // 512 blocks, 64 tokens each
    dim3 block(512);           // 8 waves
    hipLaunchKernelGGL(rvq_kernel, grid, block, 0, stream,
                       latent, projw, projb, cb, out);
}

// Round 19
// 1343.695 us; speedup vs baseline: 3.6356x; 1.3484x over previous
//
#include <hip/hip_runtime.h>
#include <float.h>
#include <stdint.h>

#define NB   8
#define NC   512
#define NT   4096
#define NCB  32
#define NK   1024
#define ND   32

// Eigen k-panel boundaries for K=512 (XLA:CPU jaxref, kc=136). VERIFIED R10.
#define KP0  0
#define KP1  136
#define KP2  272
#define KP3  408
#define KP4  512

typedef float f32x4 __attribute__((ext_vector_type(4)));
typedef short s16x8 __attribute__((ext_vector_type(8)));

// ---- XLA:CPU (Eigen) bit-exact refine models (verified R10) ------------------
__device__ __forceinline__ float dot_xla(const float* __restrict__ rf,
                                         const float* __restrict__ c) {
    float t = 0.f;
#pragma unroll
    for (int i = 0; i < ND; ++i) t = fmaf(rf[i], c[i], t);
    return t;
}
__device__ __forceinline__ float cn_xla(const float* __restrict__ c) {
    float t = 0.f;
#pragma unroll
    for (int i = 0; i < ND; ++i) t = fmaf(c[i], c[i], t);
    return t;
}
__device__ __forceinline__ float exact_d_ref(const float* __restrict__ rf,
                                             const float* __restrict__ c) {
    return __fsub_rn(cn_xla(c), __fmul_rn(2.0f, dot_xla(rf, c)));
}

// bf16 round-to-nearest-even (returns low 16 bits)
__device__ __forceinline__ uint32_t bf16rne(float f) {
    uint32_t u = __float_as_uint(f);
    return (u + 0x7FFFu + ((u >> 16) & 1u)) >> 16;
}

// write a token row (32 f32) as bf16 hi[32] + lo[32] into A_lds row
__device__ __forceinline__ void write_arow(unsigned short* arow,
                                           const float* rf) {
#pragma unroll
    for (int g = 0; g < 4; ++g) {
        s16x8 H, L;
#pragma unroll
        for (int e = 0; e < 8; ++e) {
            const float f = rf[g * 8 + e];
            const uint32_t h = bf16rne(f);
            H[e] = (short)h;
            L[e] = (short)bf16rne(f - __uint_as_float(h << 16));
        }
        *(s16x8*)&arow[g * 8]      = H;   // hi block [0..31]
        *(s16x8*)&arow[32 + g * 8] = L;   // lo block [32..63]
    }
}

// ---- prepass: convert codebook to fragment-layout bf16 hi/lo in d_ws ---------
// slot = ((stage*64 + ctile)*64 + lane); entry = 16 ushorts (hi8, lo8) where
// cand = ctile*16 + (lane&15), koct = lane>>4, elems k = koct*8+e.
__global__ void __launch_bounds__(256)
cb_prepass(const float* __restrict__ cb, unsigned short* __restrict__ bws) {
    const int flat  = blockIdx.x * 256 + threadIdx.x;   // 0..131071
    const int stage = flat >> 12;
    const int rem   = flat & 4095;
    const int ctile = rem >> 6;
    const int lane  = rem & 63;
    const int cand  = ctile * 16 + (lane & 15);
    const int koct  = lane >> 4;
    const float* src = cb + ((size_t)stage * NK + cand) * ND + koct * 8;
    unsigned short* dst = bws + (size_t)flat * 16;
    s16x8 H, L;
#pragma unroll
    for (int e = 0; e < 8; ++e) {
        const float f = src[e];
        const uint32_t h = bf16rne(f);
        H[e] = (short)h;
        L[e] = (short)bf16rne(f - __uint_as_float(h << 16));
    }
    *(s16x8*)&dst[0] = H;
    *(s16x8*)&dst[8] = L;
}

// ---- main kernel -------------------------------------------------------------
// 512 threads = 8 waves, 512 blocks (64 tokens each, token-per-lane for the
// serial phases). Scan is MFMA: D[tok][cand] = R·C^T via 16x16x32 bf16 with
// hi/lo split (3 passes, f32 accum; filter err ~3e-6 = f32-FMA-filter class).
// Residual lives in LDS (xbuf f32 exact; A_lds bf16 hi/lo fragments).
template <int PRE>
__global__ void
__attribute__((amdgpu_flat_work_group_size(512, 512)))
rvq_kernel(const float* __restrict__ latent,
           const float* __restrict__ projw,
           const float* __restrict__ projb,
           const float* __restrict__ cb,
           const unsigned short* __restrict__ bws,
           float* __restrict__ out)
{
    __shared__ float          sbuf[32 * 136];     // 17408 B: phase-B w panels
    __shared__ float          xbuf[64 * 36];      //  9216 B: live residual f32
    __shared__ float          xorig[64 * 36];     //  9216 B: original x
    __shared__ unsigned short A_lds[64 * 72];     //  9216 B: bf16 hi/lo frags
    __shared__ float          cnf[NK];            //  4096 B
    __shared__ float4         mrg[512];           //  8192 B   (total 57344 B)

    const int tid  = threadIdx.x;
    const int lane = tid & 63;
    const int wv   = tid >> 6;                        // 0..7
    const int b    = blockIdx.x >> 6;
    const int t    = ((blockIdx.x & 63) << 6) + lane; // token column

    // ---------- Phase B: projection — Eigen 4-panel kc=136 (bit-exact, R10) ---
    {
#pragma clang fp contract(off)
        const float* lat = latent + (size_t)b * NC * NT + t;
        const int d0 = wv * 4;
        float xv[4];
#pragma unroll
        for (int j = 0; j < 4; ++j) xv[j] = 0.f;
#pragma unroll 1
        for (int p = 0; p < 4; ++p) {
            const int c0  = (p == 0) ? KP0 : (p == 1) ? KP1 : (p == 2) ? KP2 : KP3;
            const int len = ((p == 0) ? KP1 : (p == 1) ? KP2 : (p == 2) ? KP3 : KP4) - c0;
            __syncthreads();
#pragma unroll
            for (int j = 0; j < 4; ++j)
                for (int cc = lane; cc < len; cc += 64)
                    sbuf[(d0 + j) * len + cc] = projw[(d0 + j) * NC + c0 + cc];
            __syncthreads();
            float acc[4];
#pragma unroll
            for (int j = 0; j < 4; ++j) acc[j] = 0.f;
#pragma unroll 2
            for (int cc = 0; cc < len; ++cc) {
                const float lv = lat[(size_t)(c0 + cc) * NT];
#pragma unroll
                for (int j = 0; j < 4; ++j)
                    acc[j] = fmaf(sbuf[(d0 + j) * len + cc], lv, acc[j]);
            }
            if (p == 0) {
#pragma unroll
                for (int j = 0; j < 4; ++j) xv[j] = acc[j];
            } else {
#pragma unroll
                for (int j = 0; j < 4; ++j) xv[j] = __fadd_rn(xv[j], acc[j]);
            }
        }
#pragma unroll
        for (int j = 0; j < 4; ++j)
            xbuf[lane * 36 + d0 + j] = __fadd_rn(xv[j], projb[d0 + j]);
    }
    __syncthreads();

    // keep original x; init A_lds fragments from x; cnorm for stage 0
    for (int i = tid; i < 64 * 36; i += 512) xorig[i] = xbuf[i];
    if (wv == 0) {
        float rf[ND];
#pragma unroll
        for (int d = 0; d < ND; ++d) rf[d] = xbuf[lane * 36 + d];
        write_arow(&A_lds[lane * 72], rf);
    }
    {
        const float* cbs = cb;
#pragma unroll 1
        for (int u = 0; u < 2; ++u) {
            const int k = u * 512 + tid;
            const float4* c4 = (const float4*)(cbs + ((size_t)k << 5));
            float ss = 0.f;
#pragma unroll 2
            for (int j = 0; j < 4; ++j) {
                const float4 va = c4[2 * j];
                const float4 vb = c4[2 * j + 1];
                ss = fmaf(va.x, va.x, ss); ss = fmaf(va.y, va.y, ss);
                ss = fmaf(va.z, va.z, ss); ss = fmaf(va.w, va.w, ss);
                ss = fmaf(vb.x, vb.x, ss); ss = fmaf(vb.y, vb.y, ss);
                ss = fmaf(vb.z, vb.z, ss); ss = fmaf(vb.w, vb.w, ss);
            }
            cnf[k] = ss;
        }
    }
    __syncthreads();

    // ---------- Phase C: 32 residual-VQ stages --------------------------------
    for (int s = 0; s < NCB; ++s) {
        const float* cbs = cb + (size_t)s * NK * ND;

        // preload this wave's per-ctile cnorm values (cand = lane&15 slice)
        float cnr[8];
#pragma unroll
        for (int ct = 0; ct < 8; ++ct)
            cnr[ct] = cnf[wv * 128 + ct * 16 + (lane & 15)];

        // ---- MFMA scan: 4 token-tiles x 8 cand-tiles ----
#pragma unroll 1
        for (int tt = 0; tt < 4; ++tt) {
            const int tok = tt * 16 + (lane & 15);
            const s16x8 ahi = *(const s16x8*)&A_lds[tok * 72 + (lane >> 4) * 8];
            const s16x8 alo = *(const s16x8*)&A_lds[tok * 72 + 32 + (lane >> 4) * 8];

            float m1[4], m2[4];
            int   i1[4], i2[4];
#pragma unroll
            for (int r = 0; r < 4; ++r) {
                m1[r] = FLT_MAX; m2[r] = FLT_MAX;
                i1[r] = 0x7fffffff; i2[r] = 0x7fffffff;
            }

#pragma unroll
            for (int ct = 0; ct < 8; ++ct) {
                s16x8 bhi, blo;
                if (PRE) {
                    const unsigned short* bp =
                        bws + (((size_t)s * 64 + wv * 8 + ct) * 64 + lane) * 16;
                    bhi = *(const s16x8*)&bp[0];
                    blo = *(const s16x8*)&bp[8];
                } else {
                    const int cand = wv * 128 + ct * 16 + (lane & 15);
                    const float* src = cbs + (size_t)cand * ND + (lane >> 4) * 8;
#pragma unroll
                    for (int e = 0; e < 8; ++e) {
                        const float f = src[e];
                        const uint32_t h = bf16rne(f);
                        bhi[e] = (short)h;
                        blo[e] = (short)bf16rne(f - __uint_as_float(h << 16));
                    }
                }
                f32x4 acc = {0.f, 0.f, 0.f, 0.f};
                acc = __builtin_amdgcn_mfma_f32_16x16x32_bf16(alo, bhi, acc, 0, 0, 0);
                acc = __builtin_amdgcn_mfma_f32_16x16x32_bf16(ahi, blo, acc, 0, 0, 0);
                acc = __builtin_amdgcn_mfma_f32_16x16x32_bf16(ahi, bhi, acc, 0, 0, 0);

                const int kc = wv * 128 + ct * 16 + (lane & 15);
#pragma unroll
                for (int r = 0; r < 4; ++r) {
                    const float d = fmaf(-2.f, acc[r], cnr[ct]);
                    const bool l1 = d < m1[r];
                    const bool l2 = d < m2[r];
                    m2[r] = l1 ? m1[r] : (l2 ? d : m2[r]);
                    i2[r] = l1 ? i1[r] : (l2 ? kc : i2[r]);
                    m1[r] = l1 ? d : m1[r];
                    i1[r] = l1 ? kc : i1[r];
                }
            }

            // butterfly top-2 merge across the 16 cand-lanes (masks 1,2,4,8)
#pragma unroll
            for (int mask = 1; mask <= 8; mask <<= 1) {
#pragma unroll
                for (int r = 0; r < 4; ++r) {
                    const float om1 = __shfl_xor(m1[r], mask);
                    const int   oi1 = __shfl_xor(i1[r], mask);
                    const float om2 = __shfl_xor(m2[r], mask);
                    const int   oi2 = __shfl_xor(i2[r], mask);
                    const bool sw = (om1 < m1[r]) || (om1 == m1[r] && oi1 < i1[r]);
                    const float w1 = sw ? om1 : m1[r];
                    const int   wi = sw ? oi1 : i1[r];
                    const float lf = sw ? m1[r] : om1;     // loser first
                    const int   li = sw ? i1[r] : oi1;
                    const float ws = sw ? om2 : m2[r];     // winner's second
                    const int   wj = sw ? oi2 : i2[r];
                    const bool s2 = (ws < lf) || (ws == lf && wj < li);
                    m1[r] = w1; i1[r] = wi;
                    m2[r] = s2 ? ws : lf;
                    i2[r] = s2 ? wj : li;
                }
            }
            if ((lane & 15) == 0) {
#pragma unroll
                for (int r = 0; r < 4; ++r) {
                    const int token = tt * 16 + 4 * (lane >> 4) + r;
                    mrg[wv * 64 + token] =
                        make_float4(m1[r], __int_as_float(i1[r]),
                                    m2[r], __int_as_float(i2[r]));
                }
            }
        }
        __syncthreads();

        // ---- wave 0: merge 8 waves, exact refine, residual update ----
        if (wv == 0) {
            float M1 = FLT_MAX, M2 = FLT_MAX;
            int   I1 = 0x7fffffff, I2 = 0x7fffffff;
#pragma unroll
            for (int w2 = 0; w2 < 8; ++w2) {
                const float4 v = mrg[w2 * 64 + lane];
#pragma unroll
                for (int h = 0; h < 2; ++h) {
                    const float m = (h == 0) ? v.x : v.z;
                    const int   i = __float_as_int((h == 0) ? v.y : v.w);
                    const bool b1 = (m < M1) || (m == M1 && i < I1);
                    const bool b2 = (m < M2) || (m == M2 && i < I2);
                    if (b1) { M2 = M1; I2 = I1; M1 = m; I1 = i; }
                    else if (b2) { M2 = m; I2 = i; }
                }
            }
            float rf[ND];
            {
                const float4* xr = (const float4*)&xbuf[lane * 36];
#pragma unroll
                for (int j = 0; j < 8; ++j) {
                    const float4 v = xr[j];
                    rf[4 * j + 0] = v.x; rf[4 * j + 1] = v.y;
                    rf[4 * j + 2] = v.z; rf[4 * j + 3] = v.w;
                }
            }
            const float d1 = exact_d_ref(rf, cbs + ((size_t)I1 << 5));
            const float d2 = exact_d_ref(rf, cbs + ((size_t)I2 << 5));
            const int kf = (d2 < d1 || (d2 == d1 && I2 < I1)) ? I2 : I1;

            {
#pragma clang fp contract(off)
                const float* cq = cbs + ((size_t)kf << 5);
#pragma unroll
                for (int d = 0; d < ND; ++d)
                    rf[d] = __fsub_rn(rf[d], cq[d]);
            }
            {
                float4* xr = (float4*)&xbuf[lane * 36];
#pragma unroll
                for (int j = 0; j < 8; ++j)
                    xr[j] = make_float4(rf[4 * j + 0], rf[4 * j + 1],
                                        rf[4 * j + 2], rf[4 * j + 3]);
            }
            write_arow(&A_lds[lane * 72], rf);
            out[(size_t)NB * ND * NT + ((size_t)s * NB + b) * NT + t] = (float)kf;
        }

        // ---- all waves: cnorm for the NEXT stage (disjoint buffers) ----
        if (s + 1 < NCB) {
            const float* cbn = cb + (size_t)(s + 1) * NK * ND;
#pragma unroll 1
            for (int u = 0; u < 2; ++u) {
                const int k = u * 512 + tid;
                const float4* c4 = (const float4*)(cbn + ((size_t)k << 5));
                float ss = 0.f;
#pragma unroll 2
                for (int j = 0; j < 4; ++j) {
                    const float4 va = c4[2 * j];
                    const float4 vb = c4[2 * j + 1];
                    ss = fmaf(va.x, va.x, ss); ss = fmaf(va.y, va.y, ss);
                    ss = fmaf(va.z, va.z, ss); ss = fmaf(va.w, va.w, ss);
                    ss = fmaf(vb.x, vb.x, ss); ss = fmaf(vb.y, vb.y, ss);
                    ss = fmaf(vb.z, vb.z, ss); ss = fmaf(vb.w, vb.w, ss);
                }
                cnf[k] = ss;
            }
        }
        __syncthreads();
    }

    // ---------- quantized output: x0 - rf_final ≈ x + (qsum - x) ----------
    if (wv == 0) {
#pragma clang fp contract(off)
#pragma unroll
        for (int d = 0; d < ND; ++d) {
            const float x0 = xorig[lane * 36 + d];
            const float rv = xbuf[lane * 36 + d];
            out[((size_t)b * ND + d) * NT + t] = __fsub_rn(x0, rv);
        }
    }
}

extern "C" void kernel_launch(void* const* d_in, const int* in_sizes, int n_in,
                              void* d_out, int out_size, void* d_ws, size_t ws_size,
                              hipStream_t stream) {
    const float* latent = (const float*)d_in[0];
    const float* projw  = (const float*)d_in[1];
    const float* projb  = (const float*)d_in[2];
    const float* cb     = (const float*)d_in[3];
    float* out = (float*)d_out;

    const size_t need = (size_t)NCB * 64 * 64 * 16 * sizeof(unsigned short); // 4 MB
    dim3 grid(NB * NT / 64), block(512);

    if (ws_size >= need) {
        unsigned short* bws = (unsigned short*)d_ws;
        hipLaunchKernelGGL(cb_prepass, dim3(512), dim3(256), 0, stream, cb, bws);
        hipLaunchKernelGGL((rvq_kernel<1>), grid, block, 0, stream,
                           latent, projw, projb, cb, bws, out);
    } else {
        hipLaunchKernelGGL((rvq_kernel<0>), grid, block, 0, stream,
                           latent, projw, projb, cb, (const unsigned short*)nullptr, out);
    }
}

// Round 20
// 1233.867 us; speedup vs baseline: 3.9592x; 1.0890x over previous
//
#include <hip/hip_runtime.h>
#include <float.h>
#include <stdint.h>

#define NB   8
#define NC   512
#define NT   4096
#define NCB  32
#define NK   1024
#define ND   32

// Eigen k-panel boundaries for K=512 (XLA:CPU jaxref, kc=136). VERIFIED R10.
#define KP0  0
#define KP1  136
#define KP2  272
#define KP3  408
#define KP4  512

typedef float f32x4 __attribute__((ext_vector_type(4)));
typedef short s16x8 __attribute__((ext_vector_type(8)));

// ---- XLA:CPU (Eigen) bit-exact refine dot (verified R10) ---------------------
__device__ __forceinline__ float dot_xla(const float* __restrict__ rf,
                                         const float* __restrict__ c) {
    float t = 0.f;
#pragma unroll
    for (int i = 0; i < ND; ++i) t = fmaf(rf[i], c[i], t);
    return t;
}

// bf16 round-to-nearest-even (returns low 16 bits)
__device__ __forceinline__ uint32_t bf16rne(float f) {
    uint32_t u = __float_as_uint(f);
    return (u + 0x7FFFu + ((u >> 16) & 1u)) >> 16;
}

// write one token's A fragments (bf16 hi/lo) into lane-linear LDS layout:
// entry (tt, l) at A_hi[(tt*64+l)*8], where l = koct*16 + (tok&15).
__device__ __forceinline__ void write_frags(unsigned short* __restrict__ A_hi,
                                            unsigned short* __restrict__ A_lo,
                                            int tok, const float* __restrict__ rf) {
    const int ttk = tok >> 4, cc = tok & 15;
#pragma unroll
    for (int q = 0; q < 4; ++q) {
        s16x8 H, L;
#pragma unroll
        for (int e = 0; e < 8; ++e) {
            const float f = rf[q * 8 + e];
            const uint32_t h = bf16rne(f);
            H[e] = (short)h;
            L[e] = (short)bf16rne(f - __uint_as_float(h << 16));
        }
        *(s16x8*)&A_hi[(ttk * 64 + q * 16 + cc) * 8] = H;
        *(s16x8*)&A_lo[(ttk * 64 + q * 16 + cc) * 8] = L;
    }
}

// ---- prepass 1: codebook -> fragment-layout bf16 hi/lo (verified R19) --------
__global__ void __launch_bounds__(256)
cb_prepass(const float* __restrict__ cb, unsigned short* __restrict__ bws) {
    const int flat  = blockIdx.x * 256 + threadIdx.x;   // 0..131071
    const int stage = flat >> 12;
    const int rem   = flat & 4095;
    const int ctile = rem >> 6;
    const int lane  = rem & 63;
    const int cand  = ctile * 16 + (lane & 15);
    const int koct  = lane >> 4;
    const float* src = cb + ((size_t)stage * NK + cand) * ND + koct * 8;
    unsigned short* dst = bws + (size_t)flat * 16;
    s16x8 H, L;
#pragma unroll
    for (int e = 0; e < 8; ++e) {
        const float f = src[e];
        const uint32_t h = bf16rne(f);
        H[e] = (short)h;
        L[e] = (short)bf16rne(f - __uint_as_float(h << 16));
    }
    *(s16x8*)&dst[0] = H;
    *(s16x8*)&dst[8] = L;
}

// ---- prepass 2: exact cnorm chains (ascending fmaf == cn_xla, bit-identical) -
__global__ void __launch_bounds__(256)
cn_prepass(const float* __restrict__ cb, float* __restrict__ cnws) {
    const int idx = blockIdx.x * 256 + threadIdx.x;     // 0..32767
    const float* c = cb + (size_t)idx * ND;
    float t = 0.f;
#pragma unroll
    for (int i = 0; i < ND; ++i) t = fmaf(c[i], c[i], t);
    cnws[idx] = t;
}

// ---- main kernel -------------------------------------------------------------
template <int PRE>
__global__ void
__attribute__((amdgpu_flat_work_group_size(512, 512)))
rvq_kernel(const float* __restrict__ latent,
           const float* __restrict__ projw,
           const float* __restrict__ projb,
           const float* __restrict__ cb,
           const unsigned short* __restrict__ bws,
           const float* __restrict__ cnws,
           float* __restrict__ out)
{
    // sbuf: phase B = w panel (17408 B); phase C carve:
    //   A_hi [0,4096) | A_lo [4096,8192) | cnf2[2][1024] [8192,16384)
    __shared__ float  sbuf[4352];
    __shared__ float  xbuf[64 * 36];     // live residual (f32 exact)
    __shared__ float  xorig[64 * 36];    // original x
    __shared__ float4 mrg[512];          // per-wave top-2 merge

    unsigned short* A_hi = (unsigned short*)sbuf;
    unsigned short* A_lo = (unsigned short*)(sbuf + 1024);
    float*          cnf2 = sbuf + 2048;

    const int tid  = threadIdx.x;
    const int lane = tid & 63;
    const int wv   = tid >> 6;                        // 0..7
    const int b    = blockIdx.x >> 6;
    const int t    = ((blockIdx.x & 63) << 6) + lane; // token column

    // ---------- Phase B: projection — Eigen 4-panel kc=136 (bit-exact, R10) ---
    {
#pragma clang fp contract(off)
        const float* lat = latent + (size_t)b * NC * NT + t;
        const int d0 = wv * 4;
        float xv[4];
#pragma unroll
        for (int j = 0; j < 4; ++j) xv[j] = 0.f;
#pragma unroll 1
        for (int p = 0; p < 4; ++p) {
            const int c0  = (p == 0) ? KP0 : (p == 1) ? KP1 : (p == 2) ? KP2 : KP3;
            const int len = ((p == 0) ? KP1 : (p == 1) ? KP2 : (p == 2) ? KP3 : KP4) - c0;
            __syncthreads();
#pragma unroll
            for (int j = 0; j < 4; ++j)
                for (int cc = lane; cc < len; cc += 64)
                    sbuf[(d0 + j) * len + cc] = projw[(d0 + j) * NC + c0 + cc];
            __syncthreads();
            float acc[4];
#pragma unroll
            for (int j = 0; j < 4; ++j) acc[j] = 0.f;
#pragma unroll 2
            for (int cc = 0; cc < len; ++cc) {
                const float lv = lat[(size_t)(c0 + cc) * NT];
#pragma unroll
                for (int j = 0; j < 4; ++j)
                    acc[j] = fmaf(sbuf[(d0 + j) * len + cc], lv, acc[j]);
            }
            if (p == 0) {
#pragma unroll
                for (int j = 0; j < 4; ++j) xv[j] = acc[j];
            } else {
#pragma unroll
                for (int j = 0; j < 4; ++j) xv[j] = __fadd_rn(xv[j], acc[j]);
            }
        }
#pragma unroll
        for (int j = 0; j < 4; ++j)
            xbuf[lane * 36 + d0 + j] = __fadd_rn(xv[j], projb[d0 + j]);
    }
    __syncthreads();                     // sbuf (w panel) reads done

    // ---------- transition: xorig, A frags, stage-0 cnorms ----------
    for (int i = tid; i < 64 * 36; i += 512) xorig[i] = xbuf[i];
    if (wv == 0) {
        float rf[ND];
#pragma unroll
        for (int d = 0; d < ND; ++d) rf[d] = xbuf[lane * 36 + d];
        write_frags(A_hi, A_lo, lane, rf);
    }
    if (PRE) {
        for (int i = tid; i < NK; i += 512) cnf2[i] = cnws[i];
    } else {
#pragma unroll 1
        for (int u = 0; u < 2; ++u) {
            const int k = u * 512 + tid;
            const float* c = cb + (size_t)k * ND;
            float ss = 0.f;
#pragma unroll
            for (int i = 0; i < ND; ++i) ss = fmaf(c[i], c[i], ss);
            cnf2[k] = ss;
        }
    }
    __syncthreads();

    // ---------- Phase C: 32 residual-VQ stages --------------------------------
    for (int s = 0; s < NCB; ++s) {
        const float* cbs = cb + (size_t)s * NK * ND;
        const int cbase = (s & 1) * NK;

        float cnr[8];
#pragma unroll
        for (int ct = 0; ct < 8; ++ct)
            cnr[ct] = cnf2[cbase + wv * 128 + ct * 16 + (lane & 15)];

        // ---- MFMA scan: 2 passes of 2 token-tiles; B prefetch double-buffered
#pragma unroll 1
        for (int th = 0; th < 2; ++th) {
            const int t0 = th * 2;
            const s16x8 ahi0 = *(const s16x8*)&A_hi[(t0 * 64 + lane) * 8];
            const s16x8 alo0 = *(const s16x8*)&A_lo[(t0 * 64 + lane) * 8];
            const s16x8 ahi1 = *(const s16x8*)&A_hi[((t0 + 1) * 64 + lane) * 8];
            const s16x8 alo1 = *(const s16x8*)&A_lo[((t0 + 1) * 64 + lane) * 8];

            float m1[2][4], m2[2][4];
            int   i1[2][4], i2[2][4];
#pragma unroll
            for (int u = 0; u < 2; ++u)
#pragma unroll
                for (int r = 0; r < 4; ++r) {
                    m1[u][r] = FLT_MAX; m2[u][r] = FLT_MAX;
                    i1[u][r] = 0x7fffffff; i2[u][r] = 0x7fffffff;
                }

            s16x8 bhiN, bloN;
            if (PRE) {
                const unsigned short* bp =
                    bws + (((size_t)s * 64 + wv * 8) * 64 + lane) * 16;
                bhiN = *(const s16x8*)&bp[0];
                bloN = *(const s16x8*)&bp[8];
            } else {
                const int cand = wv * 128 + (lane & 15);
                const float* src = cbs + (size_t)cand * ND + (lane >> 4) * 8;
#pragma unroll
                for (int e = 0; e < 8; ++e) {
                    const float f = src[e];
                    const uint32_t h = bf16rne(f);
                    bhiN[e] = (short)h;
                    bloN[e] = (short)bf16rne(f - __uint_as_float(h << 16));
                }
            }

#pragma unroll
            for (int ct = 0; ct < 8; ++ct) {
                const s16x8 bhi = bhiN, blo = bloN;
                if (ct < 7) {
                    if (PRE) {
                        const unsigned short* bp =
                            bws + (((size_t)s * 64 + wv * 8 + ct + 1) * 64 + lane) * 16;
                        bhiN = *(const s16x8*)&bp[0];
                        bloN = *(const s16x8*)&bp[8];
                    } else {
                        const int cand = wv * 128 + (ct + 1) * 16 + (lane & 15);
                        const float* src = cbs + (size_t)cand * ND + (lane >> 4) * 8;
#pragma unroll
                        for (int e = 0; e < 8; ++e) {
                            const float f = src[e];
                            const uint32_t h = bf16rne(f);
                            bhiN[e] = (short)h;
                            bloN[e] = (short)bf16rne(f - __uint_as_float(h << 16));
                        }
                    }
                }
                const int kc = wv * 128 + ct * 16 + (lane & 15);

                f32x4 acc = {0.f, 0.f, 0.f, 0.f};
                acc = __builtin_amdgcn_mfma_f32_16x16x32_bf16(alo0, bhi, acc, 0, 0, 0);
                acc = __builtin_amdgcn_mfma_f32_16x16x32_bf16(ahi0, blo, acc, 0, 0, 0);
                acc = __builtin_amdgcn_mfma_f32_16x16x32_bf16(ahi0, bhi, acc, 0, 0, 0);
#pragma unroll
                for (int r = 0; r < 4; ++r) {
                    const float d = fmaf(-2.f, acc[r], cnr[ct]);
                    const bool l1 = d < m1[0][r];
                    const bool l2 = d < m2[0][r];
                    m2[0][r] = l1 ? m1[0][r] : (l2 ? d : m2[0][r]);
                    i2[0][r] = l1 ? i1[0][r] : (l2 ? kc : i2[0][r]);
                    m1[0][r] = l1 ? d : m1[0][r];
                    i1[0][r] = l1 ? kc : i1[0][r];
                }

                f32x4 acd = {0.f, 0.f, 0.f, 0.f};
                acd = __builtin_amdgcn_mfma_f32_16x16x32_bf16(alo1, bhi, acd, 0, 0, 0);
                acd = __builtin_amdgcn_mfma_f32_16x16x32_bf16(ahi1, blo, acd, 0, 0, 0);
                acd = __builtin_amdgcn_mfma_f32_16x16x32_bf16(ahi1, bhi, acd, 0, 0, 0);
#pragma unroll
                for (int r = 0; r < 4; ++r) {
                    const float d = fmaf(-2.f, acd[r], cnr[ct]);
                    const bool l1 = d < m1[1][r];
                    const bool l2 = d < m2[1][r];
                    m2[1][r] = l1 ? m1[1][r] : (l2 ? d : m2[1][r]);
                    i2[1][r] = l1 ? i1[1][r] : (l2 ? kc : i2[1][r]);
                    m1[1][r] = l1 ? d : m1[1][r];
                    i1[1][r] = l1 ? kc : i1[1][r];
                }
            }

            // butterfly top-2 merge across the 16 cand-lanes
#pragma unroll
            for (int u = 0; u < 2; ++u) {
#pragma unroll
                for (int mask = 1; mask <= 8; mask <<= 1) {
#pragma unroll
                    for (int r = 0; r < 4; ++r) {
                        const float om1 = __shfl_xor(m1[u][r], mask);
                        const int   oi1 = __shfl_xor(i1[u][r], mask);
                        const float om2 = __shfl_xor(m2[u][r], mask);
                        const int   oi2 = __shfl_xor(i2[u][r], mask);
                        const bool sw = (om1 < m1[u][r]) ||
                                        (om1 == m1[u][r] && oi1 < i1[u][r]);
                        const float w1 = sw ? om1 : m1[u][r];
                        const int   wi = sw ? oi1 : i1[u][r];
                        const float lf = sw ? m1[u][r] : om1;
                        const int   li = sw ? i1[u][r] : oi1;
                        const float ws = sw ? om2 : m2[u][r];
                        const int   wj = sw ? oi2 : i2[u][r];
                        const bool s2 = (ws < lf) || (ws == lf && wj < li);
                        m1[u][r] = w1; i1[u][r] = wi;
                        m2[u][r] = s2 ? ws : lf;
                        i2[u][r] = s2 ? wj : li;
                    }
                }
                if ((lane & 15) == 0) {
#pragma unroll
                    for (int r = 0; r < 4; ++r) {
                        const int token = (t0 + u) * 16 + 4 * (lane >> 4) + r;
                        mrg[wv * 64 + token] =
                            make_float4(m1[u][r], __int_as_float(i1[u][r]),
                                        m2[u][r], __int_as_float(i2[u][r]));
                    }
                }
            }
        }

        // ---- cnorms for next stage into the other cnf half (pre-barrier) ----
        if (s + 1 < NCB) {
            const int nb = ((s + 1) & 1) * NK;
            if (PRE) {
                for (int i = tid; i < NK; i += 512)
                    cnf2[nb + i] = cnws[(s + 1) * NK + i];
            } else {
                const float* cbn = cb + (size_t)(s + 1) * NK * ND;
#pragma unroll 1
                for (int u = 0; u < 2; ++u) {
                    const int k = u * 512 + tid;
                    const float* c = cbn + (size_t)k * ND;
                    float ss = 0.f;
#pragma unroll
                    for (int i = 0; i < ND; ++i) ss = fmaf(c[i], c[i], ss);
                    cnf2[nb + k] = ss;
                }
            }
        }
        __syncthreads();

        // ---- wave 0: merge 8 waves, exact refine (cn from LDS), update ----
        if (wv == 0) {
            float M1 = FLT_MAX, M2 = FLT_MAX;
            int   I1 = 0x7fffffff, I2 = 0x7fffffff;
#pragma unroll
            for (int w2 = 0; w2 < 8; ++w2) {
                const float4 v = mrg[w2 * 64 + lane];
#pragma unroll
                for (int h = 0; h < 2; ++h) {
                    const float m = (h == 0) ? v.x : v.z;
                    const int   i = __float_as_int((h == 0) ? v.y : v.w);
                    const bool b1 = (m < M1) || (m == M1 && i < I1);
                    const bool b2 = (m < M2) || (m == M2 && i < I2);
                    if (b1) { M2 = M1; I2 = I1; M1 = m; I1 = i; }
                    else if (b2) { M2 = m; I2 = i; }
                }
            }
            float rf[ND];
            {
                const float4* xr = (const float4*)&xbuf[lane * 36];
#pragma unroll
                for (int j = 0; j < 8; ++j) {
                    const float4 v = xr[j];
                    rf[4 * j + 0] = v.x; rf[4 * j + 1] = v.y;
                    rf[4 * j + 2] = v.z; rf[4 * j + 3] = v.w;
                }
            }
            const float d1 = __fsub_rn(cnf2[cbase + I1],
                                       __fmul_rn(2.0f, dot_xla(rf, cbs + ((size_t)I1 << 5))));
            const float d2 = __fsub_rn(cnf2[cbase + I2],
                                       __fmul_rn(2.0f, dot_xla(rf, cbs + ((size_t)I2 << 5))));
            const int kf = (d2 < d1 || (d2 == d1 && I2 < I1)) ? I2 : I1;

            {
#pragma clang fp contract(off)
                const float* cq = cbs + ((size_t)kf << 5);
#pragma unroll
                for (int d = 0; d < ND; ++d)
                    rf[d] = __fsub_rn(rf[d], cq[d]);
            }
            {
                float4* xr = (float4*)&xbuf[lane * 36];
#pragma unroll
                for (int j = 0; j < 8; ++j)
                    xr[j] = make_float4(rf[4 * j + 0], rf[4 * j + 1],
                                        rf[4 * j + 2], rf[4 * j + 3]);
            }
            write_frags(A_hi, A_lo, lane, rf);
            out[(size_t)NB * ND * NT + ((size_t)s * NB + b) * NT + t] = (float)kf;
        }
        __syncthreads();
    }

    // ---------- quantized output: x0 - rf_final ≈ x + (qsum - x) ----------
    if (wv == 0) {
#pragma clang fp contract(off)
#pragma unroll
        for (int d = 0; d < ND; ++d) {
            const float x0 = xorig[lane * 36 + d];
            const float rv = xbuf[lane * 36 + d];
            out[((size_t)b * ND + d) * NT + t] = __fsub_rn(x0, rv);
        }
    }
}

extern "C" void kernel_launch(void* const* d_in, const int* in_sizes, int n_in,
                              void* d_out, int out_size, void* d_ws, size_t ws_size,
                              hipStream_t stream) {
    const float* latent = (const float*)d_in[0];
    const float* projw  = (const float*)d_in[1];
    const float* projb  = (const float*)d_in[2];
    const float* cb     = (const float*)d_in[3];
    float* out = (float*)d_out;

    const size_t fragsz = (size_t)NCB * 64 * 64 * 16 * sizeof(unsigned short); // 4 MB
    const size_t need   = fragsz + (size_t)NCB * NK * sizeof(float);           // +128 KB
    dim3 grid(NB * NT / 64), block(512);

    if (ws_size >= need) {
        unsigned short* bws = (unsigned short*)d_ws;
        float* cnws = (float*)((char*)d_ws + fragsz);
        hipLaunchKernelGGL(cb_prepass, dim3(512), dim3(256), 0, stream, cb, bws);
        hipLaunchKernelGGL(cn_prepass, dim3(128), dim3(256), 0, stream, cb, cnws);
        hipLaunchKernelGGL((rvq_kernel<1>), grid, block, 0, stream,
                           latent, projw, projb, cb, bws, cnws, out);
    } else {
        hipLaunchKernelGGL((rvq_kernel<0>), grid, block, 0, stream,
                           latent, projw, projb, cb,
                           (const unsigned short*)nullptr, (const float*)nullptr, out);
    }
}

// Round 22
// 681.315 us; speedup vs baseline: 7.1701x; 1.8110x over previous
//
#include <hip/hip_runtime.h>
#include <float.h>
#include <stdint.h>

#define NB   8
#define NC   512
#define NT   4096
#define NCB  32
#define NK   1024
#define ND   32

// Eigen k-panel boundaries for K=512 (XLA:CPU jaxref, kc=136). VERIFIED R10.
#define KP0  0
#define KP1  136
#define KP2  272
#define KP3  408
#define KP4  512

typedef float f32x4 __attribute__((ext_vector_type(4)));
typedef short s16x8 __attribute__((ext_vector_type(8)));

// ---- XLA:CPU (Eigen) bit-exact refine dot (verified R10) ---------------------
__device__ __forceinline__ float dot_xla(const float* __restrict__ rf,
                                         const float* __restrict__ c) {
    float t = 0.f;
#pragma unroll
    for (int i = 0; i < ND; ++i) t = fmaf(rf[i], c[i], t);
    return t;
}

// bf16 round-to-nearest-even (returns low 16 bits)
__device__ __forceinline__ uint32_t bf16rne(float f) {
    uint32_t u = __float_as_uint(f);
    return (u + 0x7FFFu + ((u >> 16) & 1u)) >> 16;
}

// ---- prepass 1: codebook -> fragment-layout bf16 hi/lo (verified R19/R20) ----
__global__ void __launch_bounds__(256)
cb_prepass(const float* __restrict__ cb, unsigned short* __restrict__ bws) {
    const int flat  = blockIdx.x * 256 + threadIdx.x;   // 0..131071
    const int stage = flat >> 12;
    const int rem   = flat & 4095;
    const int ctile = rem >> 6;
    const int lane  = rem & 63;
    const int cand  = ctile * 16 + (lane & 15);
    const int koct  = lane >> 4;
    const float* src = cb + ((size_t)stage * NK + cand) * ND + koct * 8;
    unsigned short* dst = bws + (size_t)flat * 16;
    s16x8 H, L;
#pragma unroll
    for (int e = 0; e < 8; ++e) {
        const float f = src[e];
        const uint32_t h = bf16rne(f);
        H[e] = (short)h;
        L[e] = (short)bf16rne(f - __uint_as_float(h << 16));
    }
    *(s16x8*)&dst[0] = H;
    *(s16x8*)&dst[8] = L;
}

// ---- prepass 2: exact cnorm chains (== cn_xla, bit-identical; verified R20) --
__global__ void __launch_bounds__(256)
cn_prepass(const float* __restrict__ cb, float* __restrict__ cnws) {
    const int idx = blockIdx.x * 256 + threadIdx.x;     // 0..32767
    const float* c = cb + (size_t)idx * ND;
    float t = 0.f;
#pragma unroll
    for (int i = 0; i < ND; ++i) t = fmaf(c[i], c[i], t);
    cnws[idx] = t;
}

// ---- main kernel -------------------------------------------------------------
// 256 threads = 4 waves; each wave owns 16 tokens end-to-end. The 32-stage
// loop has ZERO barriers: per stage a wave scans all 1024 candidates for its
// 16-token tile (MFMA hi/lo, B prefetched 4-deep), 16-lane butterfly gives
// global top-2 per token, lanes 0-15 do the exact-ref refine + update for
// their own token, all lanes rebuild A-frags (in registers) from own xbuf rows.
template <int PRE>
__global__ void
__launch_bounds__(256)
__attribute__((amdgpu_waves_per_eu(1, 4)))
rvq_kernel(const float* __restrict__ latent,
           const float* __restrict__ projw,
           const float* __restrict__ projb,
           const float* __restrict__ cb,
           const unsigned short* __restrict__ bws,
           const float* __restrict__ cnws,
           float* __restrict__ out)
{
    __shared__ float sbuf[32 * 136];   // 17408 B: phase-B w panels
    __shared__ float xbuf[64 * 36];    //  9216 B: live residual (f32 exact)
    __shared__ float xorig[64 * 36];   //  9216 B: original x   (35840 B total)

    const int tid   = threadIdx.x;
    const int lane  = tid & 63;
    const int wv    = tid >> 6;                 // 0..3
    const int lc    = lane & 15;
    const int koct  = lane >> 4;
    const int b     = blockIdx.x >> 6;
    const int tbase = (blockIdx.x & 63) << 6;
    const int t     = tbase + lane;             // phase-B token (one per lane)

    // ---------- Phase B: projection — Eigen 4-panel kc=136 (bit-exact, R10) ---
    {
#pragma clang fp contract(off)
        const float* lat = latent + (size_t)b * NC * NT + t;
        const int d0 = wv * 8;
        float xv[8];
#pragma unroll
        for (int j = 0; j < 8; ++j) xv[j] = 0.f;
#pragma unroll 1
        for (int p = 0; p < 4; ++p) {
            const int c0  = (p == 0) ? KP0 : (p == 1) ? KP1 : (p == 2) ? KP2 : KP3;
            const int len = ((p == 0) ? KP1 : (p == 1) ? KP2 : (p == 2) ? KP3 : KP4) - c0;
            __syncthreads();
#pragma unroll
            for (int j = 0; j < 8; ++j)
                for (int cc = lane; cc < len; cc += 64)
                    sbuf[(d0 + j) * len + cc] = projw[(d0 + j) * NC + c0 + cc];
            __syncthreads();
            float acc[8];
#pragma unroll
            for (int j = 0; j < 8; ++j) acc[j] = 0.f;
#pragma unroll 2
            for (int cc = 0; cc < len; ++cc) {
                const float lv = lat[(size_t)(c0 + cc) * NT];
#pragma unroll
                for (int j = 0; j < 8; ++j)
                    acc[j] = fmaf(sbuf[(d0 + j) * len + cc], lv, acc[j]);
            }
            if (p == 0) {
#pragma unroll
                for (int j = 0; j < 8; ++j) xv[j] = acc[j];
            } else {
#pragma unroll
                for (int j = 0; j < 8; ++j) xv[j] = __fadd_rn(xv[j], acc[j]);
            }
        }
#pragma unroll
        for (int j = 0; j < 8; ++j)
            xbuf[lane * 36 + d0 + j] = __fadd_rn(xv[j], projb[d0 + j]);
    }
    __syncthreads();            // last barrier: xbuf complete; waves go async now

    // wave-own xorig copy (rows [wv*16, wv*16+16) = floats [wv*576, +576))
    for (int i = lane; i < 576; i += 64) xorig[wv * 576 + i] = xbuf[wv * 576 + i];

    // ---------- Phase C: 32 residual-VQ stages, barrier-free ------------------
    const int myrow = wv * 16 + lc;             // this lane's A-frag token row
    s16x8 ahi, alo;
    {   // initial A fragments from xbuf (own rows)
        const float* xr = &xbuf[myrow * 36 + koct * 8];
#pragma unroll
        for (int e = 0; e < 8; ++e) {
            const float f = xr[e];
            const uint32_t h = bf16rne(f);
            ahi[e] = (short)h;
            alo[e] = (short)bf16rne(f - __uint_as_float(h << 16));
        }
    }

    for (int s = 0; s < NCB; ++s) {
        const float* cbs = cb + (size_t)s * NK * ND;

        float m1[4], m2[4];
        int   i1[4], i2[4];
#pragma unroll
        for (int r = 0; r < 4; ++r) {
            m1[r] = FLT_MAX; m2[r] = FLT_MAX;
            i1[r] = 0x7fffffff; i2[r] = 0x7fffffff;
        }

        s16x8 bh0, bl0, bh1, bl1, bh2, bl2, bh3, bl3;
        float cn0, cn1, cn2, cn3;

#define ISSUE(CT, BH, BL, CN)                                                   \
        if (PRE) {                                                              \
            const unsigned short* bp =                                          \
                bws + (((size_t)s * 64 + (CT)) * 64 + lane) * 16;               \
            BH = *(const s16x8*)&bp[0];                                         \
            BL = *(const s16x8*)&bp[8];                                         \
            CN = cnws[s * NK + ((CT) << 4) + lc];                               \
        } else {                                                                \
            const float* src = cbs + (size_t)(((CT) << 4) + lc) * ND;           \
            float vv[32];                                                       \
            _Pragma("unroll")                                                   \
            for (int q = 0; q < 8; ++q)                                         \
                *(float4*)&vv[q * 4] = *(const float4*)&src[q * 4];             \
            _Pragma("unroll")                                                   \
            for (int e = 0; e < 8; ++e) {                                       \
                const float f = vv[koct * 8 + e];                               \
                const uint32_t h = bf16rne(f);                                  \
                BH[e] = (short)h;                                               \
                BL[e] = (short)bf16rne(f - __uint_as_float(h << 16));           \
            }                                                                   \
            float ssx = 0.f;                                                    \
            _Pragma("unroll")                                                   \
            for (int e = 0; e < 32; ++e) ssx = fmaf(vv[e], vv[e], ssx);         \
            CN = ssx;                                                           \
        }

#define PROC(CT, BH, BL, CN) {                                                  \
            f32x4 acc = {0.f, 0.f, 0.f, 0.f};                                   \
            acc = __builtin_amdgcn_mfma_f32_16x16x32_bf16(alo, BH, acc, 0, 0, 0);\
            acc = __builtin_amdgcn_mfma_f32_16x16x32_bf16(ahi, BL, acc, 0, 0, 0);\
            acc = __builtin_amdgcn_mfma_f32_16x16x32_bf16(ahi, BH, acc, 0, 0, 0);\
            const int kc = ((CT) << 4) + lc;                                    \
            _Pragma("unroll")                                                   \
            for (int r = 0; r < 4; ++r) {                                       \
                const float d = fmaf(-2.f, acc[r], CN);                         \
                const bool l1 = d < m1[r];                                      \
                const bool l2 = d < m2[r];                                      \
                m2[r] = l1 ? m1[r] : (l2 ? d : m2[r]);                          \
                i2[r] = l1 ? i1[r] : (l2 ? kc : i2[r]);                         \
                m1[r] = l1 ? d : m1[r];                                         \
                i1[r] = l1 ? kc : i1[r];                                        \
            } }

        ISSUE(0, bh0, bl0, cn0);
        ISSUE(1, bh1, bl1, cn1);
        ISSUE(2, bh2, bl2, cn2);
        ISSUE(3, bh3, bl3, cn3);

#pragma unroll 1
        for (int ct = 0; ct < 64; ct += 4) {
            PROC(ct + 0, bh0, bl0, cn0); ISSUE((ct + 4) & 63, bh0, bl0, cn0);
            PROC(ct + 1, bh1, bl1, cn1); ISSUE((ct + 5) & 63, bh1, bl1, cn1);
            PROC(ct + 2, bh2, bl2, cn2); ISSUE((ct + 6) & 63, bh2, bl2, cn2);
            PROC(ct + 3, bh3, bl3, cn3); ISSUE((ct + 7) & 63, bh3, bl3, cn3);
        }
#undef ISSUE
#undef PROC

        // ---- 16-lane butterfly: global top-2 per row over all 1024 ----
#pragma unroll
        for (int mask = 1; mask <= 8; mask <<= 1) {
#pragma unroll
            for (int r = 0; r < 4; ++r) {
                const float om1 = __shfl_xor(m1[r], mask);
                const int   oi1 = __shfl_xor(i1[r], mask);
                const float om2 = __shfl_xor(m2[r], mask);
                const int   oi2 = __shfl_xor(i2[r], mask);
                const bool sw = (om1 < m1[r]) || (om1 == m1[r] && oi1 < i1[r]);
                const float w1 = sw ? om1 : m1[r];
                const int   wi = sw ? oi1 : i1[r];
                const float lf = sw ? m1[r] : om1;
                const int   li = sw ? i1[r] : oi1;
                const float ws = sw ? om2 : m2[r];
                const int   wj = sw ? oi2 : i2[r];
                const bool s2 = (ws < lf) || (ws == lf && wj < li);
                m1[r] = w1; i1[r] = wi;
                m2[r] = s2 ? ws : lf;
                i2[r] = s2 ? wj : li;
            }
        }

        // ---- redistribute token tk -> lane tk ----
        const int src = (lane >> 2) << 4;       // source lane for this group
        float rm1[4], rm2[4]; int ri1[4], ri2[4];
#pragma unroll
        for (int r = 0; r < 4; ++r) {
            rm1[r] = __shfl(m1[r], src);
            ri1[r] = __shfl(i1[r], src);
            rm2[r] = __shfl(m2[r], src);
            ri2[r] = __shfl(i2[r], src);
        }
        const int rr = lane & 3;
        const int   I1 = rr == 0 ? ri1[0] : rr == 1 ? ri1[1] : rr == 2 ? ri1[2] : ri1[3];
        const int   I2 = rr == 0 ? ri2[0] : rr == 1 ? ri2[1] : rr == 2 ? ri2[2] : ri2[3];

        // ---- lanes 0-15: exact-ref refine + residual update (own token) ----
        if (lane < 16) {
            const int tok = wv * 16 + lane;
            float rf[ND];
            {
                const float4* xr = (const float4*)&xbuf[tok * 36];
#pragma unroll
                for (int j = 0; j < 8; ++j) {
                    const float4 v = xr[j];
                    rf[4 * j + 0] = v.x; rf[4 * j + 1] = v.y;
                    rf[4 * j + 2] = v.z; rf[4 * j + 3] = v.w;
                }
            }
            const float* cA = cbs + ((size_t)I1 << 5);
            const float* cB = cbs + ((size_t)I2 << 5);
            float cnA, cnB;
            if (PRE) {
                cnA = cnws[s * NK + I1];
                cnB = cnws[s * NK + I2];
            } else {
                float a = 0.f, bq = 0.f;
#pragma unroll
                for (int i = 0; i < ND; ++i) a  = fmaf(cA[i], cA[i], a);
#pragma unroll
                for (int i = 0; i < ND; ++i) bq = fmaf(cB[i], cB[i], bq);
                cnA = a; cnB = bq;
            }
            const float d1 = __fsub_rn(cnA, __fmul_rn(2.0f, dot_xla(rf, cA)));
            const float d2 = __fsub_rn(cnB, __fmul_rn(2.0f, dot_xla(rf, cB)));
            const int kf = (d2 < d1 || (d2 == d1 && I2 < I1)) ? I2 : I1;

            {
#pragma clang fp contract(off)
                const float* cq = cbs + ((size_t)kf << 5);
#pragma unroll
                for (int d = 0; d < ND; ++d)
                    rf[d] = __fsub_rn(rf[d], cq[d]);
            }
            {
                float4* xr = (float4*)&xbuf[tok * 36];
#pragma unroll
                for (int j = 0; j < 8; ++j)
                    xr[j] = make_float4(rf[4 * j + 0], rf[4 * j + 1],
                                        rf[4 * j + 2], rf[4 * j + 3]);
            }
            out[(size_t)NB * ND * NT + ((size_t)s * NB + b) * NT + tbase + tok] = (float)kf;
        }

        // ---- all lanes: rebuild A fragments from (updated) own xbuf rows ----
        {
            const float* xr = &xbuf[myrow * 36 + koct * 8];
#pragma unroll
            for (int e = 0; e < 8; ++e) {
                const float f = xr[e];
                const uint32_t h = bf16rne(f);
                ahi[e] = (short)h;
                alo[e] = (short)bf16rne(f - __uint_as_float(h << 16));
            }
        }
    }

    // ---------- quantized output: x0 - rf_final (own tokens, no barrier) ------
    if (lane < 16) {
        const int tok = wv * 16 + lane;
        const int tt  = tbase + tok;
        {
#pragma clang fp contract(off)
#pragma unroll
            for (int d = 0; d < ND; ++d) {
                const float x0 = xorig[tok * 36 + d];
                const float rv = xbuf[tok * 36 + d];
                out[((size_t)b * ND + d) * NT + tt] = __fsub_rn(x0, rv);
            }
        }
    }
}

extern "C" void kernel_launch(void* const* d_in, const int* in_sizes, int n_in,
                              void* d_out, int out_size, void* d_ws, size_t ws_size,
                              hipStream_t stream) {
    const float* latent = (const float*)d_in[0];
    const float* projw  = (const float*)d_in[1];
    const float* projb  = (const float*)d_in[2];
    const float* cb     = (const float*)d_in[3];
    float* out = (float*)d_out;

    const size_t fragsz = (size_t)NCB * 64 * 64 * 16 * sizeof(unsigned short); // 4 MB
    const size_t need   = fragsz + (size_t)NCB * NK * sizeof(float);           // +128 KB
    dim3 grid(NB * NT / 64), block(256);

    if (ws_size >= need) {
        unsigned short* bws = (unsigned short*)d_ws;
        float* cnws = (float*)((char*)d_ws + fragsz);
        hipLaunchKernelGGL(cb_prepass, dim3(512), dim3(256), 0, stream, cb, bws);
        hipLaunchKernelGGL(cn_prepass, dim3(128), dim3(256), 0, stream, cb, cnws);
        hipLaunchKernelGGL((rvq_kernel<1>), grid, block, 0, stream,
                           latent, projw, projb, cb, bws, cnws, out);
    } else {
        hipLaunchKernelGGL((rvq_kernel<0>), grid, block, 0, stream,
                           latent, projw, projb, cb,
                           (const unsigned short*)nullptr, (const float*)nullptr, out);
    }
}